// Round 1
// baseline (287.846 us; speedup 1.0000x reference)
//
#include <hip/hip_runtime.h>

#define LEAKY 0.2f
#define CAP 1024

struct GemmJob {
  const float* X; const float* W; const float* B; float* Y; int M; int relu;
};

// Y[m,n] = X[m,:] . W[n,:] + B[n], K=N=128. 64 rows/block, 256 threads.
// Each thread: 8 rows x 4 cols register tile; X and W chunks staged transposed in LDS.
__global__ __launch_bounds__(256) void gemm3_kernel(GemmJob j0, GemmJob j1, GemmJob j2) {
  GemmJob J = (blockIdx.y == 0) ? j0 : (blockIdx.y == 1) ? j1 : j2;
  const int row0 = blockIdx.x * 64;
  if (row0 >= J.M) return;
  __shared__ float XsT[32][64];    // [k][r]
  __shared__ float WTs[32][128];   // [k][n]
  const int tid = threadIdx.x;
  const int tx = tid & 31;         // col group: cols tx*4 .. tx*4+3
  const int ty = tid >> 5;         // row group: rows ty*8 .. ty*8+7
  float4 acc[8];
#pragma unroll
  for (int i = 0; i < 8; i++) acc[i] = make_float4(0.f, 0.f, 0.f, 0.f);

  const int rS  = tid >> 2;        // 0..63 staging row
  const int kbX = (tid & 3) * 8;   // X staging k base
  const int nS  = tid >> 1;        // 0..127 staging col for W
  const int kbW = (tid & 1) * 16;  // W staging k base

  for (int k0 = 0; k0 < 128; k0 += 32) {
    int rr = row0 + rS; if (rr >= J.M) rr = J.M - 1;
    const float* xp = J.X + (size_t)rr * 128 + k0 + kbX;
    float4 x0 = *(const float4*)xp;
    float4 x1 = *(const float4*)(xp + 4);
    XsT[kbX + 0][rS] = x0.x; XsT[kbX + 1][rS] = x0.y;
    XsT[kbX + 2][rS] = x0.z; XsT[kbX + 3][rS] = x0.w;
    XsT[kbX + 4][rS] = x1.x; XsT[kbX + 5][rS] = x1.y;
    XsT[kbX + 6][rS] = x1.z; XsT[kbX + 7][rS] = x1.w;

    const float* wp = J.W + (size_t)nS * 128 + k0 + kbW;
    float4 w0 = *(const float4*)wp;
    float4 w1 = *(const float4*)(wp + 4);
    float4 w2 = *(const float4*)(wp + 8);
    float4 w3 = *(const float4*)(wp + 12);
    WTs[kbW + 0][nS] = w0.x; WTs[kbW + 1][nS] = w0.y; WTs[kbW + 2][nS] = w0.z; WTs[kbW + 3][nS] = w0.w;
    WTs[kbW + 4][nS] = w1.x; WTs[kbW + 5][nS] = w1.y; WTs[kbW + 6][nS] = w1.z; WTs[kbW + 7][nS] = w1.w;
    WTs[kbW + 8][nS] = w2.x; WTs[kbW + 9][nS] = w2.y; WTs[kbW +10][nS] = w2.z; WTs[kbW +11][nS] = w2.w;
    WTs[kbW +12][nS] = w3.x; WTs[kbW +13][nS] = w3.y; WTs[kbW +14][nS] = w3.z; WTs[kbW +15][nS] = w3.w;
    __syncthreads();

#pragma unroll
    for (int k = 0; k < 32; k++) {
      float4 wv = *(const float4*)&WTs[k][tx * 4];
      float4 xa = *(const float4*)&XsT[k][ty * 8];
      float4 xb = *(const float4*)&XsT[k][ty * 8 + 4];
      acc[0].x += xa.x * wv.x; acc[0].y += xa.x * wv.y; acc[0].z += xa.x * wv.z; acc[0].w += xa.x * wv.w;
      acc[1].x += xa.y * wv.x; acc[1].y += xa.y * wv.y; acc[1].z += xa.y * wv.z; acc[1].w += xa.y * wv.w;
      acc[2].x += xa.z * wv.x; acc[2].y += xa.z * wv.y; acc[2].z += xa.z * wv.z; acc[2].w += xa.z * wv.w;
      acc[3].x += xa.w * wv.x; acc[3].y += xa.w * wv.y; acc[3].z += xa.w * wv.z; acc[3].w += xa.w * wv.w;
      acc[4].x += xb.x * wv.x; acc[4].y += xb.x * wv.y; acc[4].z += xb.x * wv.z; acc[4].w += xb.x * wv.w;
      acc[5].x += xb.y * wv.x; acc[5].y += xb.y * wv.y; acc[5].z += xb.y * wv.z; acc[5].w += xb.y * wv.w;
      acc[6].x += xb.z * wv.x; acc[6].y += xb.z * wv.y; acc[6].z += xb.z * wv.z; acc[6].w += xb.z * wv.w;
      acc[7].x += xb.w * wv.x; acc[7].y += xb.w * wv.y; acc[7].z += xb.w * wv.z; acc[7].w += xb.w * wv.w;
    }
    __syncthreads();
  }

  float4 bv = make_float4(0.f, 0.f, 0.f, 0.f);
  if (J.B) bv = *(const float4*)(J.B + tx * 4);
#pragma unroll
  for (int i = 0; i < 8; i++) {
    int r = row0 + ty * 8 + i;
    if (r < J.M) {
      float4 o;
      o.x = acc[i].x + bv.x; o.y = acc[i].y + bv.y;
      o.z = acc[i].z + bv.z; o.w = acc[i].w + bv.w;
      if (J.relu) {
        o.x = fmaxf(o.x, 0.f); o.y = fmaxf(o.y, 0.f);
        o.z = fmaxf(o.z, 0.f); o.w = fmaxf(o.w, 0.f);
      }
      *(float4*)(J.Y + (size_t)r * 128 + tx * 4) = o;
    }
  }
}

// v[k][h] = sum_d W[(h*32+d)*128 + k] * att[h*32+d]  (folds att into W for logit GEMV)
__global__ void prep_v(const float* __restrict__ Wsrc, const float* __restrict__ attsrc,
                       const float* __restrict__ Wdst, const float* __restrict__ attdst,
                       float* __restrict__ vsrc, float* __restrict__ vdst) {
  int tid = threadIdx.x;             // 256
  int which = tid >> 7;
  int k = tid & 127;
  const float* W = which ? Wdst : Wsrc;
  const float* att = which ? attdst : attsrc;
  float* v = which ? vdst : vsrc;
  float s[4] = {0.f, 0.f, 0.f, 0.f};
#pragma unroll
  for (int h = 0; h < 4; h++)
    for (int d = 0; d < 32; d++)
      s[h] += W[(size_t)(h * 32 + d) * 128 + k] * att[h * 32 + d];
#pragma unroll
  for (int h = 0; h < 4; h++) v[k * 4 + h] = s[h];
}

// a[n][h] = x[n,:] . v[:,h]; one wave per node.
__global__ __launch_bounds__(256) void attn_logits(const float* __restrict__ X,
                                                   const float* __restrict__ v,
                                                   float* __restrict__ a, int M) {
  __shared__ float vs[128 * 4];
  for (int i = threadIdx.x; i < 512; i += 256) vs[i] = v[i];
  __syncthreads();
  int wv = threadIdx.x >> 6, lane = threadIdx.x & 63;
  int n = blockIdx.x * 4 + wv;
  if (n >= M) return;
  float x0 = X[(size_t)n * 128 + lane];
  float x1 = X[(size_t)n * 128 + 64 + lane];
  float4 va = *(const float4*)&vs[lane * 4];
  float4 vb = *(const float4*)&vs[(64 + lane) * 4];
  float p0 = x0 * va.x + x1 * vb.x;
  float p1 = x0 * va.y + x1 * vb.y;
  float p2 = x0 * va.z + x1 * vb.z;
  float p3 = x0 * va.w + x1 * vb.w;
#pragma unroll
  for (int off = 32; off > 0; off >>= 1) {
    p0 += __shfl_xor(p0, off, 64);
    p1 += __shfl_xor(p1, off, 64);
    p2 += __shfl_xor(p2, off, 64);
    p3 += __shfl_xor(p3, off, 64);
  }
  if (lane == 0) {
    float4 o = make_float4(p0, p1, p2, p3);
    *(float4*)(a + (size_t)n * 4) = o;
  }
}

__global__ void hist_kernel(const int* __restrict__ edge_dst, int* __restrict__ counts, int E) {
  int e = blockIdx.x * 256 + threadIdx.x;
  if (e < E) atomicAdd(&counts[edge_dst[e]], 1);
}

// single-block exclusive scan of counts[0..n) -> rowptr & cursor; rowptr[n]=total
__global__ __launch_bounds__(256) void scan_kernel(const int* __restrict__ counts,
                                                   int* __restrict__ rowptr,
                                                   int* __restrict__ cursor, int n) {
  __shared__ int wsum[4];
  __shared__ int carry_s;
  int tid = threadIdx.x, lane = tid & 63, wv = tid >> 6;
  if (tid == 0) carry_s = 0;
  __syncthreads();
  for (int base = 0; base < n; base += 2048) {
    int idx0 = base + tid * 8;
    int v[8]; int s = 0;
#pragma unroll
    for (int j = 0; j < 8; j++) {
      int i = idx0 + j;
      v[j] = (i < n) ? counts[i] : 0;
      s += v[j];
    }
    int incl = s;
#pragma unroll
    for (int off = 1; off < 64; off <<= 1) {
      int t = __shfl_up(incl, off, 64);
      if (lane >= off) incl += t;
    }
    if (lane == 63) wsum[wv] = incl;
    __syncthreads();
    int wpre = 0;
    for (int w = 0; w < wv; w++) wpre += wsum[w];
    int carry = carry_s;
    int excl = carry + wpre + incl - s;
#pragma unroll
    for (int j = 0; j < 8; j++) {
      int i = idx0 + j;
      if (i < n) { rowptr[i] = excl; cursor[i] = excl; }
      excl += v[j];
    }
    __syncthreads();
    if (tid == 0) carry_s = carry + wsum[0] + wsum[1] + wsum[2] + wsum[3];
    __syncthreads();
  }
  if (tid == 0) rowptr[n] = carry_s;
}

__global__ void scatter_kernel(const int* __restrict__ edge_src, const int* __restrict__ edge_dst,
                               int* __restrict__ cursor, int* __restrict__ sorted_src, int E) {
  int e = blockIdx.x * 256 + threadIdx.x;
  if (e < E) {
    int d = edge_dst[e];
    int pos = atomicAdd(&cursor[d], 1);
    sorted_src[pos] = edge_src[e];
  }
}

// One block (128 thr) per dst node. Pass1: softmax denominators (no max-shift needed:
// shift-invariant, epsilon diff ~1e-18 rel). Pass2: out = inv*sum(w*u_src[src]) - sA*u_pred + self.
__global__ __launch_bounds__(128) void agg_kernel(
    const int* __restrict__ rowptr, const int* __restrict__ sorted_src,
    const float* __restrict__ a_s, const float* __restrict__ a_d,
    const float* __restrict__ u_src, const float* __restrict__ u_pred,
    const float* __restrict__ self_o, float* __restrict__ out) {
  int dst = blockIdx.x;
  int tid = threadIdx.x;
  __shared__ float wbuf[CAP * 4];
  __shared__ int srcbuf[CAP];
  __shared__ float4 red4[2];
  __shared__ float inv_s[4], sA_s[4];
  int start = rowptr[dst], end = rowptr[dst + 1];
  int deg = end - start;
  float4 ad4 = *(const float4*)(a_d + (size_t)dst * 4);
  float s0 = 0.f, s1 = 0.f, s2 = 0.f, s3 = 0.f;
  for (int i = tid; i < deg; i += 128) {
    int src = sorted_src[start + i];
    float4 as4 = *(const float4*)(a_s + (size_t)src * 4);
    float l0 = as4.x + ad4.x; l0 = l0 > 0.f ? l0 : LEAKY * l0;
    float l1 = as4.y + ad4.y; l1 = l1 > 0.f ? l1 : LEAKY * l1;
    float l2 = as4.z + ad4.z; l2 = l2 > 0.f ? l2 : LEAKY * l2;
    float l3 = as4.w + ad4.w; l3 = l3 > 0.f ? l3 : LEAKY * l3;
    float w0 = __expf(l0), w1 = __expf(l1), w2 = __expf(l2), w3 = __expf(l3);
    if (i < CAP) {
      wbuf[i * 4 + 0] = w0; wbuf[i * 4 + 1] = w1;
      wbuf[i * 4 + 2] = w2; wbuf[i * 4 + 3] = w3;
      srcbuf[i] = src;
    }
    s0 += w0; s1 += w1; s2 += w2; s3 += w3;
  }
  int lane = tid & 63, wv = tid >> 6;
#pragma unroll
  for (int off = 32; off > 0; off >>= 1) {
    s0 += __shfl_xor(s0, off, 64);
    s1 += __shfl_xor(s1, off, 64);
    s2 += __shfl_xor(s2, off, 64);
    s3 += __shfl_xor(s3, off, 64);
  }
  if (lane == 0) red4[wv] = make_float4(s0, s1, s2, s3);
  __syncthreads();
  if (tid == 0) {
    float dx = red4[0].x + red4[1].x;
    float dy = red4[0].y + red4[1].y;
    float dz = red4[0].z + red4[1].z;
    float dw = red4[0].w + red4[1].w;
    inv_s[0] = 1.f / (dx + 1e-16f); sA_s[0] = dx * inv_s[0];
    inv_s[1] = 1.f / (dy + 1e-16f); sA_s[1] = dy * inv_s[1];
    inv_s[2] = 1.f / (dz + 1e-16f); sA_s[2] = dz * inv_s[2];
    inv_s[3] = 1.f / (dw + 1e-16f); sA_s[3] = dw * inv_s[3];
  }
  __syncthreads();
  int h = tid >> 5;
  float adh = (h == 0) ? ad4.x : (h == 1) ? ad4.y : (h == 2) ? ad4.z : ad4.w;
  float acc = 0.f;
  int cap = deg < CAP ? deg : CAP;
  for (int i = 0; i < cap; i++) {
    int src = srcbuf[i];
    float w = wbuf[i * 4 + h];
    acc += w * u_src[(size_t)src * 128 + tid];
  }
  for (int i = CAP; i < deg; i++) {  // fallback for huge degree (rare/never at E/N=64)
    int src = sorted_src[start + i];
    float l = a_s[(size_t)src * 4 + h] + adh;
    l = l > 0.f ? l : LEAKY * l;
    acc += __expf(l) * u_src[(size_t)src * 128 + tid];
  }
  float res = acc * inv_s[h] - sA_s[h] * u_pred[(size_t)dst * 128 + tid]
            + self_o[(size_t)dst * 128 + tid];
  out[(size_t)dst * 128 + tid] = res;
}

extern "C" void kernel_launch(void* const* d_in, const int* in_sizes, int n_in,
                              void* d_out, int out_size, void* d_ws, size_t ws_size,
                              hipStream_t stream) {
  const float* x_src   = (const float*)d_in[0];
  const float* x_dst   = (const float*)d_in[1];
  const float* W_pred1 = (const float*)d_in[2];
  const float* b_pred1 = (const float*)d_in[3];
  const float* W_pred2 = (const float*)d_in[4];
  const float* b_pred2 = (const float*)d_in[5];
  const float* W_res   = (const float*)d_in[6];
  const float* W_src   = (const float*)d_in[7];
  const float* W_dst   = (const float*)d_in[8];
  const float* att_src = (const float*)d_in[9];
  const float* att_dst = (const float*)d_in[10];
  const float* W_self  = (const float*)d_in[11];
  const float* b_self  = (const float*)d_in[12];
  const int* edge_src  = (const int*)d_in[13];
  const int* edge_dst  = (const int*)d_in[14];
  int Ns = in_sizes[0] / 128;
  int Nd = in_sizes[1] / 128;
  int E  = in_sizes[13];
  float* out = (float*)d_out;

  char* ws = (char*)d_ws;
  auto alloc = [&](size_t bytes) -> char* {
    char* p = ws;
    ws += (bytes + 255) & ~(size_t)255;
    return p;
  };
  float* pred1  = (float*)alloc((size_t)Nd * 128 * 4);
  float* pred   = (float*)alloc((size_t)Nd * 128 * 4);
  float* u_src  = (float*)alloc((size_t)Ns * 128 * 4);
  float* u_pred = (float*)alloc((size_t)Nd * 128 * 4);
  float* self_o = (float*)alloc((size_t)Nd * 128 * 4);
  float* a_s    = (float*)alloc((size_t)Ns * 4 * 4);
  float* a_d    = (float*)alloc((size_t)Nd * 4 * 4);
  float* v_src  = (float*)alloc(128 * 4 * 4);
  float* v_dst  = (float*)alloc(128 * 4 * 4);
  int* counts   = (int*)alloc((size_t)Nd * 4);
  int* rowptr   = (int*)alloc((size_t)(Nd + 1) * 4);
  int* cursor   = (int*)alloc((size_t)Nd * 4);
  int* sorted_src = (int*)alloc((size_t)E * 4);

  hipMemsetAsync(counts, 0, (size_t)Nd * sizeof(int), stream);

  hipLaunchKernelGGL(prep_v, dim3(1), dim3(256), 0, stream,
                     W_src, att_src, W_dst, att_dst, v_src, v_dst);

  GemmJob jA{ x_dst, W_pred1, b_pred1, pred1, Nd, 1 };
  GemmJob jB{ x_src, W_res,   nullptr, u_src, Ns, 0 };
  GemmJob jC{ x_dst, W_self,  b_self,  self_o, Nd, 0 };
  int maxM = Ns > Nd ? Ns : Nd;
  hipLaunchKernelGGL(gemm3_kernel, dim3((maxM + 63) / 64, 3), dim3(256), 0, stream, jA, jB, jC);

  GemmJob jD{ pred1, W_pred2, b_pred2, pred, Nd, 0 };
  hipLaunchKernelGGL(gemm3_kernel, dim3((Nd + 63) / 64, 1), dim3(256), 0, stream, jD, jD, jD);

  GemmJob jE{ pred, W_res, nullptr, u_pred, Nd, 0 };
  hipLaunchKernelGGL(gemm3_kernel, dim3((Nd + 63) / 64, 1), dim3(256), 0, stream, jE, jE, jE);

  hipLaunchKernelGGL(attn_logits, dim3((Ns + 3) / 4), dim3(256), 0, stream, x_src, v_src, a_s, Ns);
  hipLaunchKernelGGL(attn_logits, dim3((Nd + 3) / 4), dim3(256), 0, stream, x_dst, v_dst, a_d, Nd);

  hipLaunchKernelGGL(hist_kernel, dim3((E + 255) / 256), dim3(256), 0, stream, edge_dst, counts, E);
  hipLaunchKernelGGL(scan_kernel, dim3(1), dim3(256), 0, stream, counts, rowptr, cursor, Nd);
  hipLaunchKernelGGL(scatter_kernel, dim3((E + 255) / 256), dim3(256), 0, stream,
                     edge_src, edge_dst, cursor, sorted_src, E);

  hipLaunchKernelGGL(agg_kernel, dim3(Nd), dim3(128), 0, stream,
                     rowptr, sorted_src, a_s, a_d, u_src, u_pred, self_o, out);
}

// Round 2
// 250.251 us; speedup vs baseline: 1.1502x; 1.1502x over previous
//
#include <hip/hip_runtime.h>

#define LEAKY 0.2f
#define CAP 160

struct GemmJob {
  const float* X; const float* W; const float* B; float* Y; int M; int relu;
};

// ---------------- device helpers ----------------

// Y[m,n] = X[m,:] . W[n,:] + B[n], K=N=128. 64-row tile at row0, 256 threads.
__device__ __forceinline__ void gemm_block(
    const float* __restrict__ X, const float* __restrict__ W,
    const float* __restrict__ B, float* __restrict__ Y,
    int M, int relu, int row0, float* XsT /*[32*64]*/, float* WTs /*[32*128]*/) {
  if (row0 >= M) return;
  const int tid = threadIdx.x;
  const int tx = tid & 31;         // cols tx*4..tx*4+3
  const int ty = tid >> 5;         // rows ty*8..ty*8+7
  float4 acc[8];
#pragma unroll
  for (int i = 0; i < 8; i++) acc[i] = make_float4(0.f, 0.f, 0.f, 0.f);

  const int rS  = tid >> 2;        // 0..63
  const int kbX = (tid & 3) * 8;
  const int nS  = tid >> 1;        // 0..127
  const int kbW = (tid & 1) * 16;

  for (int k0 = 0; k0 < 128; k0 += 32) {
    int rr = row0 + rS; if (rr >= M) rr = M - 1;
    const float* xp = X + (size_t)rr * 128 + k0 + kbX;
    float4 x0 = *(const float4*)xp;
    float4 x1 = *(const float4*)(xp + 4);
    XsT[(kbX + 0) * 64 + rS] = x0.x; XsT[(kbX + 1) * 64 + rS] = x0.y;
    XsT[(kbX + 2) * 64 + rS] = x0.z; XsT[(kbX + 3) * 64 + rS] = x0.w;
    XsT[(kbX + 4) * 64 + rS] = x1.x; XsT[(kbX + 5) * 64 + rS] = x1.y;
    XsT[(kbX + 6) * 64 + rS] = x1.z; XsT[(kbX + 7) * 64 + rS] = x1.w;

    const float* wp = W + (size_t)nS * 128 + k0 + kbW;
    float4 w0 = *(const float4*)wp;
    float4 w1 = *(const float4*)(wp + 4);
    float4 w2 = *(const float4*)(wp + 8);
    float4 w3 = *(const float4*)(wp + 12);
    WTs[(kbW + 0) * 128 + nS] = w0.x; WTs[(kbW + 1) * 128 + nS] = w0.y;
    WTs[(kbW + 2) * 128 + nS] = w0.z; WTs[(kbW + 3) * 128 + nS] = w0.w;
    WTs[(kbW + 4) * 128 + nS] = w1.x; WTs[(kbW + 5) * 128 + nS] = w1.y;
    WTs[(kbW + 6) * 128 + nS] = w1.z; WTs[(kbW + 7) * 128 + nS] = w1.w;
    WTs[(kbW + 8) * 128 + nS] = w2.x; WTs[(kbW + 9) * 128 + nS] = w2.y;
    WTs[(kbW +10) * 128 + nS] = w2.z; WTs[(kbW +11) * 128 + nS] = w2.w;
    WTs[(kbW +12) * 128 + nS] = w3.x; WTs[(kbW +13) * 128 + nS] = w3.y;
    WTs[(kbW +14) * 128 + nS] = w3.z; WTs[(kbW +15) * 128 + nS] = w3.w;
    __syncthreads();

#pragma unroll
    for (int k = 0; k < 32; k++) {
      float4 wv = *(const float4*)&WTs[k * 128 + tx * 4];
      float4 xa = *(const float4*)&XsT[k * 64 + ty * 8];
      float4 xb = *(const float4*)&XsT[k * 64 + ty * 8 + 4];
      acc[0].x += xa.x * wv.x; acc[0].y += xa.x * wv.y; acc[0].z += xa.x * wv.z; acc[0].w += xa.x * wv.w;
      acc[1].x += xa.y * wv.x; acc[1].y += xa.y * wv.y; acc[1].z += xa.y * wv.z; acc[1].w += xa.y * wv.w;
      acc[2].x += xa.z * wv.x; acc[2].y += xa.z * wv.y; acc[2].z += xa.z * wv.z; acc[2].w += xa.z * wv.w;
      acc[3].x += xa.w * wv.x; acc[3].y += xa.w * wv.y; acc[3].z += xa.w * wv.z; acc[3].w += xa.w * wv.w;
      acc[4].x += xb.x * wv.x; acc[4].y += xb.x * wv.y; acc[4].z += xb.x * wv.z; acc[4].w += xb.x * wv.w;
      acc[5].x += xb.y * wv.x; acc[5].y += xb.y * wv.y; acc[5].z += xb.y * wv.z; acc[5].w += xb.y * wv.w;
      acc[6].x += xb.z * wv.x; acc[6].y += xb.z * wv.y; acc[6].z += xb.z * wv.z; acc[6].w += xb.z * wv.w;
      acc[7].x += xb.w * wv.x; acc[7].y += xb.w * wv.y; acc[7].z += xb.w * wv.z; acc[7].w += xb.w * wv.w;
    }
    __syncthreads();
  }

  float4 bv = make_float4(0.f, 0.f, 0.f, 0.f);
  if (B) bv = *(const float4*)(B + tx * 4);
#pragma unroll
  for (int i = 0; i < 8; i++) {
    int r = row0 + ty * 8 + i;
    if (r < M) {
      float4 o;
      o.x = acc[i].x + bv.x; o.y = acc[i].y + bv.y;
      o.z = acc[i].z + bv.z; o.w = acc[i].w + bv.w;
      if (relu) {
        o.x = fmaxf(o.x, 0.f); o.y = fmaxf(o.y, 0.f);
        o.z = fmaxf(o.z, 0.f); o.w = fmaxf(o.w, 0.f);
      }
      *(float4*)(Y + (size_t)r * 128 + tx * 4) = o;
    }
  }
}

// a[n][h] = x[n,:] . v[:,h]; one wave per node, 4 nodes per 256-thr block.
__device__ __forceinline__ void attn_block(const float* __restrict__ X,
                                           const float* __restrict__ v,
                                           float* __restrict__ a, int M, int blk,
                                           float* vs /*512 floats*/) {
  for (int i = threadIdx.x; i < 512; i += 256) vs[i] = v[i];
  __syncthreads();
  int wv = threadIdx.x >> 6, lane = threadIdx.x & 63;
  int n = blk * 4 + wv;
  if (n >= M) return;
  float x0 = X[(size_t)n * 128 + lane];
  float x1 = X[(size_t)n * 128 + 64 + lane];
  float4 va = *(const float4*)&vs[lane * 4];
  float4 vb = *(const float4*)&vs[(64 + lane) * 4];
  float p0 = x0 * va.x + x1 * vb.x;
  float p1 = x0 * va.y + x1 * vb.y;
  float p2 = x0 * va.z + x1 * vb.z;
  float p3 = x0 * va.w + x1 * vb.w;
#pragma unroll
  for (int off = 32; off > 0; off >>= 1) {
    p0 += __shfl_xor(p0, off, 64);
    p1 += __shfl_xor(p1, off, 64);
    p2 += __shfl_xor(p2, off, 64);
    p3 += __shfl_xor(p3, off, 64);
  }
  if (lane == 0) *(float4*)(a + (size_t)n * 4) = make_float4(p0, p1, p2, p3);
}

// single-block exclusive scan of counts[0..n) -> rowptr & cursor; rowptr[n]=total
__device__ __forceinline__ void scan_block(const int* __restrict__ counts,
                                           int* __restrict__ rowptr,
                                           int* __restrict__ cursor, int n,
                                           int* iw /*>=5 ints*/) {
  int tid = threadIdx.x, lane = tid & 63, wv = tid >> 6;
  if (tid == 0) iw[4] = 0;
  __syncthreads();
  for (int base = 0; base < n; base += 2048) {
    int idx0 = base + tid * 8;
    int v[8]; int s = 0;
#pragma unroll
    for (int j = 0; j < 8; j++) {
      int i = idx0 + j;
      v[j] = (i < n) ? counts[i] : 0;
      s += v[j];
    }
    int incl = s;
#pragma unroll
    for (int off = 1; off < 64; off <<= 1) {
      int t = __shfl_up(incl, off, 64);
      if (lane >= off) incl += t;
    }
    if (lane == 63) iw[wv] = incl;
    __syncthreads();
    int wpre = 0;
    for (int w = 0; w < wv; w++) wpre += iw[w];
    int carry = iw[4];
    int excl = carry + wpre + incl - s;
#pragma unroll
    for (int j = 0; j < 8; j++) {
      int i = idx0 + j;
      if (i < n) { rowptr[i] = excl; cursor[i] = excl; }
      excl += v[j];
    }
    __syncthreads();
    if (tid == 0) iw[4] = carry + iw[0] + iw[1] + iw[2] + iw[3];
    __syncthreads();
  }
  if (tid == 0) rowptr[n] = iw[4];
}

// ---------------- fused kernels ----------------

// block 0: v_src/v_dst (att folded into W). blocks 1..65: Wc = W_res@W_pred2 and
// bc = W_res@b_pred2. blocks >=66: histogram of edge_dst.
__global__ __launch_bounds__(256) void phase1(
    const float* __restrict__ Wsrc, const float* __restrict__ attsrc,
    const float* __restrict__ Wdst, const float* __restrict__ attdst,
    const float* __restrict__ W_res, const float* __restrict__ W2,
    const float* __restrict__ b2,
    float* __restrict__ v_src, float* __restrict__ v_dst,
    float* __restrict__ Wc, float* __restrict__ bc,
    const int* __restrict__ edge_dst, int* __restrict__ counts, int E) {
  int bx = blockIdx.x, tid = threadIdx.x;
  if (bx == 0) {
    int which = tid >> 7, k = tid & 127;
    const float* W = which ? Wdst : Wsrc;
    const float* att = which ? attdst : attsrc;
    float* v = which ? v_dst : v_src;
    float s[4] = {0.f, 0.f, 0.f, 0.f};
#pragma unroll
    for (int h = 0; h < 4; h++)
      for (int d = 0; d < 32; d++)
        s[h] += W[(size_t)(h * 32 + d) * 128 + k] * att[h * 32 + d];
#pragma unroll
    for (int h = 0; h < 4; h++) v[k * 4 + h] = s[h];
  } else if (bx <= 65) {
    int id = (bx - 1) * 256 + tid;
    if (id < 16384) {
      int o = id >> 7, j = id & 127;
      float s = 0.f;
      for (int i = 0; i < 128; i++) s += W_res[(size_t)o * 128 + i] * W2[(size_t)i * 128 + j];
      Wc[(size_t)o * 128 + j] = s;
    } else if (id < 16512) {
      int o = id - 16384;
      float s = 0.f;
      for (int i = 0; i < 128; i++) s += W_res[(size_t)o * 128 + i] * b2[i];
      bc[o] = s;
    }
  } else {
    int e = (bx - 66) * 256 + tid;
    if (e < E) atomicAdd(&counts[edge_dst[e]], 1);
  }
}

// blocks [0,3G): the 3 independent GEMMs; [3G,3G+As): attn src; next Ad: attn dst;
// last block: scan (overlaps with GEMM work).
__global__ __launch_bounds__(256) void phase2(
    GemmJob j0, GemmJob j1, GemmJob j2,
    const float* __restrict__ x_src, const float* __restrict__ x_dst,
    const float* __restrict__ v_src, const float* __restrict__ v_dst,
    float* __restrict__ a_s, float* __restrict__ a_d,
    const int* __restrict__ counts, int* __restrict__ rowptr, int* __restrict__ cursor,
    int Ns, int Nd, int G, int As, int Ad) {
  __shared__ float smem[32 * 64 + 32 * 128];
  int bx = blockIdx.x;
  if (bx < 3 * G) {
    GemmJob J = (bx < G) ? j0 : (bx < 2 * G) ? j1 : j2;
    int row0 = (bx % G) * 64;
    gemm_block(J.X, J.W, J.B, J.Y, J.M, J.relu, row0, smem, smem + 2048);
  } else if (bx < 3 * G + As) {
    attn_block(x_src, v_src, a_s, Ns, bx - 3 * G, smem);
  } else if (bx < 3 * G + As + Ad) {
    attn_block(x_dst, v_dst, a_d, Nd, bx - 3 * G - As, smem);
  } else {
    scan_block(counts, rowptr, cursor, Nd, (int*)smem);
  }
}

// blocks [0,G): u_pred = relu1@Wc.T + bc; rest: scatter into CSR.
__global__ __launch_bounds__(256) void phase3(
    GemmJob j, const int* __restrict__ edge_src, const int* __restrict__ edge_dst,
    int* __restrict__ cursor, int* __restrict__ sorted_src, int E, int G) {
  __shared__ float smem[32 * 64 + 32 * 128];
  int bx = blockIdx.x;
  if (bx < G) {
    gemm_block(j.X, j.W, j.B, j.Y, j.M, j.relu, bx * 64, smem, smem + 2048);
  } else {
    int e = (bx - G) * 256 + threadIdx.x;
    if (e < E) {
      int d = edge_dst[e];
      int pos = atomicAdd(&cursor[d], 1);
      sorted_src[pos] = edge_src[e];
    }
  }
}

// One block (128 thr) per dst. Pass1: softmax denom (shift-free: exp of raw leaky
// logits; eps diff ~1e-18 rel). Pass2: out = inv*sum(w*u_src[src]) - sA*u_pred + self.
__global__ __launch_bounds__(128) void agg_kernel(
    const int* __restrict__ rowptr, const int* __restrict__ sorted_src,
    const float* __restrict__ a_s, const float* __restrict__ a_d,
    const float* __restrict__ u_src, const float* __restrict__ u_pred,
    const float* __restrict__ self_o, float* __restrict__ out) {
  int dst = blockIdx.x;
  int tid = threadIdx.x;
  __shared__ float wbuf[CAP * 4];
  __shared__ int srcbuf[CAP];
  __shared__ float4 red4[2];
  __shared__ float inv_s[4], sA_s[4];
  int start = rowptr[dst], end = rowptr[dst + 1];
  int deg = end - start;
  float4 ad4 = *(const float4*)(a_d + (size_t)dst * 4);
  float s0 = 0.f, s1 = 0.f, s2 = 0.f, s3 = 0.f;
  for (int i = tid; i < deg; i += 128) {
    int src = sorted_src[start + i];
    float4 as4 = *(const float4*)(a_s + (size_t)src * 4);
    float l0 = as4.x + ad4.x; l0 = l0 > 0.f ? l0 : LEAKY * l0;
    float l1 = as4.y + ad4.y; l1 = l1 > 0.f ? l1 : LEAKY * l1;
    float l2 = as4.z + ad4.z; l2 = l2 > 0.f ? l2 : LEAKY * l2;
    float l3 = as4.w + ad4.w; l3 = l3 > 0.f ? l3 : LEAKY * l3;
    float w0 = __expf(l0), w1 = __expf(l1), w2 = __expf(l2), w3 = __expf(l3);
    if (i < CAP) {
      wbuf[i * 4 + 0] = w0; wbuf[i * 4 + 1] = w1;
      wbuf[i * 4 + 2] = w2; wbuf[i * 4 + 3] = w3;
      srcbuf[i] = src;
    }
    s0 += w0; s1 += w1; s2 += w2; s3 += w3;
  }
  int lane = tid & 63, wv = tid >> 6;
#pragma unroll
  for (int off = 32; off > 0; off >>= 1) {
    s0 += __shfl_xor(s0, off, 64);
    s1 += __shfl_xor(s1, off, 64);
    s2 += __shfl_xor(s2, off, 64);
    s3 += __shfl_xor(s3, off, 64);
  }
  if (lane == 0) red4[wv] = make_float4(s0, s1, s2, s3);
  __syncthreads();
  if (tid == 0) {
    float dx = red4[0].x + red4[1].x;
    float dy = red4[0].y + red4[1].y;
    float dz = red4[0].z + red4[1].z;
    float dw = red4[0].w + red4[1].w;
    inv_s[0] = 1.f / (dx + 1e-16f); sA_s[0] = dx * inv_s[0];
    inv_s[1] = 1.f / (dy + 1e-16f); sA_s[1] = dy * inv_s[1];
    inv_s[2] = 1.f / (dz + 1e-16f); sA_s[2] = dz * inv_s[2];
    inv_s[3] = 1.f / (dw + 1e-16f); sA_s[3] = dw * inv_s[3];
  }
  __syncthreads();
  int h = tid >> 5;
  float adh = (h == 0) ? ad4.x : (h == 1) ? ad4.y : (h == 2) ? ad4.z : ad4.w;
  int cap = deg < CAP ? deg : CAP;
  float acc0 = 0.f, acc1 = 0.f;
  int i = 0;
  for (; i + 1 < cap; i += 2) {
    int sA = srcbuf[i], sB = srcbuf[i + 1];
    float wA = wbuf[i * 4 + h], wB = wbuf[(i + 1) * 4 + h];
    acc0 += wA * u_src[(size_t)sA * 128 + tid];
    acc1 += wB * u_src[(size_t)sB * 128 + tid];
  }
  if (i < cap) acc0 += wbuf[i * 4 + h] * u_src[(size_t)srcbuf[i] * 128 + tid];
  for (int k = CAP; k < deg; k++) {  // rare overflow path, recompute weight
    int src = sorted_src[start + k];
    float l = a_s[(size_t)src * 4 + h] + adh;
    l = l > 0.f ? l : LEAKY * l;
    acc0 += __expf(l) * u_src[(size_t)src * 128 + tid];
  }
  float acc = acc0 + acc1;
  float res = acc * inv_s[h] - sA_s[h] * u_pred[(size_t)dst * 128 + tid]
            + self_o[(size_t)dst * 128 + tid];
  out[(size_t)dst * 128 + tid] = res;
}

extern "C" void kernel_launch(void* const* d_in, const int* in_sizes, int n_in,
                              void* d_out, int out_size, void* d_ws, size_t ws_size,
                              hipStream_t stream) {
  const float* x_src   = (const float*)d_in[0];
  const float* x_dst   = (const float*)d_in[1];
  const float* W_pred1 = (const float*)d_in[2];
  const float* b_pred1 = (const float*)d_in[3];
  const float* W_pred2 = (const float*)d_in[4];
  const float* b_pred2 = (const float*)d_in[5];
  const float* W_res   = (const float*)d_in[6];
  const float* W_src   = (const float*)d_in[7];
  const float* W_dst   = (const float*)d_in[8];
  const float* att_src = (const float*)d_in[9];
  const float* att_dst = (const float*)d_in[10];
  const float* W_self  = (const float*)d_in[11];
  const float* b_self  = (const float*)d_in[12];
  const int* edge_src  = (const int*)d_in[13];
  const int* edge_dst  = (const int*)d_in[14];
  int Ns = in_sizes[0] / 128;
  int Nd = in_sizes[1] / 128;
  int E  = in_sizes[13];
  float* out = (float*)d_out;

  char* ws = (char*)d_ws;
  auto alloc = [&](size_t bytes) -> char* {
    char* p = ws;
    ws += (bytes + 255) & ~(size_t)255;
    return p;
  };
  float* relu1  = (float*)alloc((size_t)Nd * 128 * 4);
  float* u_src  = (float*)alloc((size_t)Ns * 128 * 4);
  float* u_pred = (float*)alloc((size_t)Nd * 128 * 4);
  float* self_o = (float*)alloc((size_t)Nd * 128 * 4);
  float* a_s    = (float*)alloc((size_t)Ns * 4 * 4);
  float* a_d    = (float*)alloc((size_t)Nd * 4 * 4);
  float* v_src  = (float*)alloc(128 * 4 * 4);
  float* v_dst  = (float*)alloc(128 * 4 * 4);
  float* Wc     = (float*)alloc(128 * 128 * 4);
  float* bc     = (float*)alloc(128 * 4);
  int* counts   = (int*)alloc((size_t)Nd * 4);
  int* rowptr   = (int*)alloc((size_t)(Nd + 1) * 4);
  int* cursor   = (int*)alloc((size_t)Nd * 4);
  int* sorted_src = (int*)alloc((size_t)E * 4);

  hipMemsetAsync(counts, 0, (size_t)Nd * sizeof(int), stream);

  int histB = (E + 255) / 256;
  hipLaunchKernelGGL(phase1, dim3(66 + histB), dim3(256), 0, stream,
                     W_src, att_src, W_dst, att_dst, W_res, W_pred2, b_pred2,
                     v_src, v_dst, Wc, bc, edge_dst, counts, E);

  int maxM = Ns > Nd ? Ns : Nd;
  int G  = (maxM + 63) / 64;
  int As = (Ns + 3) / 4;
  int Ad = (Nd + 3) / 4;
  GemmJob jA{ x_dst, W_pred1, b_pred1, relu1, Nd, 1 };
  GemmJob jB{ x_src, W_res,   nullptr, u_src, Ns, 0 };
  GemmJob jC{ x_dst, W_self,  b_self,  self_o, Nd, 0 };
  hipLaunchKernelGGL(phase2, dim3(3 * G + As + Ad + 1), dim3(256), 0, stream,
                     jA, jB, jC, x_src, x_dst, v_src, v_dst, a_s, a_d,
                     counts, rowptr, cursor, Ns, Nd, G, As, Ad);

  GemmJob jD{ relu1, Wc, bc, u_pred, Nd, 0 };
  int Gd = (Nd + 63) / 64;
  hipLaunchKernelGGL(phase3, dim3(Gd + histB), dim3(256), 0, stream,
                     jD, edge_src, edge_dst, cursor, sorted_src, E, Gd);

  hipLaunchKernelGGL(agg_kernel, dim3(Nd), dim3(128), 0, stream,
                     rowptr, sorted_src, a_s, a_d, u_src, u_pred, self_o, out);
}